// Round 6
// baseline (1068.755 us; speedup 1.0000x reference)
//
#include <hip/hip_runtime.h>

// SpatialPool: fm [B=16, C=512, H=38, W=38] f32, replication pad 1,
// out[b, (h*W+w)*9*C + k*C + c] = fm[b, c, clamp(h+k/3-1), clamp(w+k%3-1)]
//
// R6 DIAGNOSTIC: every structure (R1-R5) lands at kernel ~180us (~2.5 TB/s
// apparent) while pure-store fill hits 6.3 TB/s on the same buffer. Theory:
// TCC write-allocate-with-fetch adds a hidden 426 MB RFO read stream
// (-> real traffic ~900 MB @ ~5 TB/s, uniform across R1-R5 since the write
// footprint is identical). Test: write output TWICE (idempotent) —
// pass 1 plain stores, pass 2 global_store_dword sc0 sc1 nt (no-allocate
// bypass, the fill's policy). Dispatch ~270-380us -> enters rocprof top-5:
//   H1 RFO+bypass-works: dur~275, FETCH~470MB, WRITE~852MB
//   H2 RFO+bypass-fails: dur~360, FETCH~900MB, WRITE~852MB
//   H3 no-RFO (drain-bound): dur~360, FETCH<150MB, WRITE~852MB

#define BB 16
#define CC 512
#define HH 38
#define WW 38
#define HW (HH * WW)      // 1444
#define KK 9
#define NT 256
#define NW4 10            // w in groups of 4 (last group = 2)

__global__ __launch_bounds__(NT) void spatial_pool_scatter2(
    const float* __restrict__ fm, float* __restrict__ out)
{
    const int blk   = blockIdx.x;
    const int w4    = blk % NW4;
    const int t     = blk / NW4;
    const int chalf = t & 1;
    const int bh    = t >> 1;
    const int h     = bh % HH;
    const int b     = bh / HH;
    const int c     = chalf * NT + threadIdx.x;

    const int w0 = w4 * 4;
    const int nw = (w4 == NW4 - 1) ? 2 : 4;

    // ---- read once ----
    const float* src = fm + ((size_t)(b * CC + c)) * HW + h * WW + w0;
    float v[4];
    {
        float2 r0 = *(const float2*)src;
        v[0] = r0.x; v[1] = r0.y;
        if (nw == 4) {
            float2 r1 = *(const float2*)(src + 2);
            v[2] = r1.x; v[3] = r1.y;
        }
    }

    // ---- h-target list: exactly 3 ----
    int hrow[3];
    {
        int n = 0;
        #pragma unroll
        for (int di = 0; di < 3; ++di) {
            int hm = h + 1 - di;
            if (0 <= hm && hm < HH) { hrow[n] = (b * HW + hm * WW) * KK + di * 3; n++; }
        }
        if (h == 0)      { hrow[n] = (b * HW) * KK; n++; }
        if (h == HH - 1) { hrow[n] = (b * HW + (HH - 1) * WW) * KK + 6; n++; }
    }

    for (int wi = 0; wi < nw; ++wi) {
        const int w = w0 + wi;
        int woff[3];
        {
            int m = 0;
            #pragma unroll
            for (int dj = 0; dj < 3; ++dj) {
                int wm = w + 1 - dj;
                if (0 <= wm && wm < WW) { woff[m] = wm * KK + dj; m++; }
            }
            if (w == 0)      { woff[m] = 0; m++; }
            if (w == WW - 1) { woff[m] = (WW - 1) * KK + 2; m++; }
        }
        const float val = v[wi];

        // ---- pass 1: plain stores (default cache policy) ----
        #pragma unroll
        for (int i = 0; i < 3; ++i) {
            #pragma unroll
            for (int j = 0; j < 3; ++j) {
                unsigned idx = (unsigned)(hrow[i] + woff[j]) * (unsigned)CC + (unsigned)c;
                out[(size_t)idx] = val;
            }
        }
        // ---- pass 2: same values, no-allocate bypass stores (sc0 sc1 nt) ----
        #pragma unroll
        for (int i = 0; i < 3; ++i) {
            #pragma unroll
            for (int j = 0; j < 3; ++j) {
                unsigned idx = (unsigned)(hrow[i] + woff[j]) * (unsigned)CC + (unsigned)c;
                float* p = out + (size_t)idx;
                asm volatile("global_store_dword %0, %1, off sc0 sc1 nt"
                             :: "v"(p), "v"(val) : "memory");
            }
        }
    }
}

extern "C" void kernel_launch(void* const* d_in, const int* in_sizes, int n_in,
                              void* d_out, int out_size, void* d_ws, size_t ws_size,
                              hipStream_t stream) {
    const float* fm = (const float*)d_in[0];
    float* out = (float*)d_out;
    dim3 grid(NW4 * 2 * BB * HH);   // 12160 blocks
    dim3 block(NT);
    spatial_pool_scatter2<<<grid, block, 0, stream>>>(fm, out);
}

// Round 7
// 451.167 us; speedup vs baseline: 2.3689x; 2.3689x over previous
//
#include <hip/hip_runtime.h>

// SpatialPool: fm [B=16, C=512, H=38, W=38] f32, replication pad 1,
// out[b, (h*W+w)*9*C + k*C + c] = fm[b, c, clamp(h+k/3-1), clamp(w+k%3-1)]
//
// R6 diagnostic: no RFO (FETCH 165MB), no write amplification (WRITE=2x426MB
// exact), fixed bench overhead ~342us -> R1-R5 kernels were ~120us = 4.9 TB/s
// (78% of achievable), NOT 3 TB/s. Dominant remaining loss: read overfetch
// 165MB vs 47MB input (input lines fetched by 3-4 XCDs due to w4-split).
//
// R7: block = (b,h), full 512-c. Each thread reads its whole 38-float row
// ONCE (within-thread line reuse via L1), scatters 342 nt stores. Each input
// line is touched by exactly one block -> FETCH ~60-90MB. Per (h',w') target
// the block writes 3 consecutive k's x 512 c = 6KB contiguous.

#define BB 16
#define CC 512
#define HH 38
#define WW 38
#define HW (HH * WW)      // 1444
#define KK 9
#define NT 512

__global__ __launch_bounds__(NT) void spatial_pool_scatter(
    const float* __restrict__ fm, float* __restrict__ out)
{
    const int bh = blockIdx.x;          // 0..607
    const int h  = bh % HH;
    const int b  = bh / HH;
    const int c  = threadIdx.x;         // 0..511, lane-consecutive

    // ---- read own row once: 19 x float2 (8B-aligned), L1 serves line reuse ----
    const float* src = fm + ((size_t)(b * CC + c)) * HW + h * WW;
    float v[WW];
    #pragma unroll
    for (int i = 0; i < WW / 2; ++i) {
        const float2 r = *((const float2*)src + i);
        v[2 * i + 0] = r.x;
        v[2 * i + 1] = r.y;
    }

    // ---- h-target list: exactly 3 (clamp extras rebalance) ----
    // hrow = (b*HW + h'*WW)*9 + di*3
    int hrow[3];
    {
        int n = 0;
        #pragma unroll
        for (int di = 0; di < 3; ++di) {
            int hm = h + 1 - di;
            if (0 <= hm && hm < HH) { hrow[n] = (b * HW + hm * WW) * KK + di * 3; n++; }
        }
        if (h == 0)      { hrow[n] = (b * HW) * KK; n++; }                      // di=0,h'=0
        if (h == HH - 1) { hrow[n] = (b * HW + (HH - 1) * WW) * KK + 6; n++; }  // di=2,h'=37
    }

    // ---- scatter: full w-unroll -> all w-edge logic & woff are compile-time ----
    float* outc = out + c;
    #pragma unroll
    for (int w = 0; w < WW; ++w) {
        int woff[3];   // woff = w'*9 + dj, exactly 3 targets
        int m = 0;
        #pragma unroll
        for (int dj = 0; dj < 3; ++dj) {
            int wm = w + 1 - dj;
            if (0 <= wm && wm < WW) { woff[m] = wm * KK + dj; m++; }
        }
        if (w == 0)      { woff[m] = 0; m++; }                 // dj=0,w'=0
        if (w == WW - 1) { woff[m] = (WW - 1) * KK + 2; m++; } // dj=2,w'=37
        const float val = v[w];
        #pragma unroll
        for (int i = 0; i < 3; ++i) {
            #pragma unroll
            for (int j = 0; j < 3; ++j) {
                unsigned idx = (unsigned)(hrow[i] + woff[j]) * (unsigned)CC;
                __builtin_nontemporal_store(val, outc + (size_t)idx);
            }
        }
    }
}

extern "C" void kernel_launch(void* const* d_in, const int* in_sizes, int n_in,
                              void* d_out, int out_size, void* d_ws, size_t ws_size,
                              hipStream_t stream) {
    const float* fm = (const float*)d_in[0];
    float* out = (float*)d_out;
    dim3 grid(BB * HH);    // 608 blocks, all co-resident
    dim3 block(NT);
    spatial_pool_scatter<<<grid, block, 0, stream>>>(fm, out);
}